// Round 8
// baseline (948.702 us; speedup 1.0000x reference)
//
#include <hip/hip_runtime.h>

typedef __attribute__((ext_vector_type(8))) __bf16 bf16x8;
typedef __attribute__((ext_vector_type(4))) float f32x4;
typedef unsigned short u16;
typedef unsigned int u32;

__device__ __forceinline__ u16 f2bf(float x){
  u32 u = __float_as_uint(x);
  return (u16)((u + 0x7fffu + ((u >> 16) & 1u)) >> 16);
}
__device__ __forceinline__ u32 pkbf(float lo, float hi){
  u32 r; asm("v_cvt_pk_bf16_f32 %0, %1, %2" : "=v"(r) : "v"(lo), "v"(hi)); return r;
}

union FragU { uint4 u4; bf16x8 bf; };

__device__ __forceinline__ bf16x8 lds_frag(const unsigned char* smem, int off, int row, int strideB, int kElem){
  int byte = (row * strideB + kElem * 2) ^ ((row & 7) << 4);
  FragU f; f.u4 = *reinterpret_cast<const uint4*>(smem + off + byte);
  return f.bf;
}

typedef __attribute__((address_space(3))) unsigned char lds_u8;
typedef __attribute__((address_space(1))) const unsigned char g_u8;
__device__ __forceinline__ void glds16(const void* g, void* l){
  __builtin_amdgcn_global_load_lds((g_u8*)g, (lds_u8*)l, 16, 0, 0);
}

__global__ void prep_weights(const float* __restrict__ wq, const float* __restrict__ wp,
                             u16* __restrict__ wqb, u16* __restrict__ wpb){
  int i = blockIdx.x * 256 + threadIdx.x;
  wqb[i] = f2bf(wq[i]);              // grid sized exactly for 442368
  if (i < 147456) wpb[i] = f2bf(wp[i]);
}

// x f32 -> bf16, linear [147456][384]
__global__ void prep_x(const float* __restrict__ x, u16* __restrict__ xb){
  size_t i = ((size_t)blockIdx.x * 256 + threadIdx.x) * 8;
  float4 f0 = *reinterpret_cast<const float4*>(x + i);
  float4 f1 = *reinterpret_cast<const float4*>(x + i + 4);
  uint4 q;
  q.x = pkbf(f0.x, f0.y); q.y = pkbf(f0.z, f0.w);
  q.z = pkbf(f1.x, f1.y); q.w = pkbf(f1.z, f1.w);
  *reinterpret_cast<uint4*>(xb + i) = q;
}

// ======================================================================
// K2 v8: qkv GEMM, B panel [192][384] FULLY resident in LDS (staged once,
// ONE barrier), then a barrier-free k-loop: A per-lane register frags from
// xb (1-tile prefetch, counted vmcnt, no barrier), B from swizzled LDS
// (3 ds_read_b128 per 12 MFMA). Flat grid 6912 with XCD co-location: the
// 6 (sec,ny) variants of one 128-row block run on the SAME XCD -> A hits L2.
// ======================================================================
#define T8C 147456      // cos table (288 f32)
#define T8S 148608      // sin table -> 149760
__launch_bounds__(512, 2)
__global__ void qkv_gemm3(const u16* __restrict__ xb, const u16* __restrict__ wqb,
                          const float* __restrict__ bq, float* __restrict__ out,
                          u16* __restrict__ vws)
{
  __shared__ __align__(16) unsigned char smem[149760];
  const int tid  = threadIdx.x;
  const int wave = tid >> 6;
  const int lane = tid & 63;
  const int l15  = lane & 15;
  const int lhi  = lane >> 4;
  const int wr   = wave >> 2;           // 0..1 : 64-row half
  const int wc   = wave & 3;            // 0..3 : 48-col quarter

  // XCD co-location: logical l = xcd*864 + i ; 6 variants of bx adjacent
  const int bid = blockIdx.x;           // 0..6911
  const int l   = (bid & 7) * 864 + (bid >> 3);
  const int bx  = l / 6;                // 0..1151 : 128-row block
  const int v6  = l - bx * 6;
  const int sec = v6 >> 1;              // 0=q,1=k,2=v
  const int ny  = v6 & 1;               // 192-col half

  const size_t row0 = (size_t)bx * 128;
  const int a    = bx / 3;              // global image-row index (0..383)
  const int bcol = bx - 3 * a;
  const int bIm  = a / 192;
  const int hh   = a % 192;
  const int rh   = (hh >= 3) ? hh - 3 : hh + 189;   // rolled row
  const int wi   = rh / 6;
  const int r6   = rh - wi * 6;                      // window-row of all tokens
  const int bwin = bIm * 1024 + wi * 32;

  float* tabc = reinterpret_cast<float*>(smem + T8C);
  float* tabs = reinterpret_cast<float*>(smem + T8S);
  if (tid < 288){
    int pos = tid >> 4, m = tid & 15;
    float pv = (pos < 6) ? (float)pos : (float)(pos - 6);
    float ang = pv * __expf(-(float)m * 0.5756462732485114f); // 10000^(-m/16)
    tabc[tid] = cosf(ang);
    tabs[tid] = sinf(ang);
  }

  // ---- stage entire B panel [192 n][384 k] bf16, pre-swizzled source ----
  // 9216 x 16B chunks; dest linear (row*768 + p*16); read-side XOR ((n&7)<<4)
  const u16* bsec = wqb + (size_t)(sec * 384 + ny * 192) * 384;
  #pragma unroll
  for (int it = 0; it < 18; ++it){
    int c   = it * 512 + tid;
    int row = c / 48;
    int p   = c - row * 48;
    int s   = (p & ~7) | ((p & 7) ^ (row & 7));
    glds16(bsec + (size_t)row * 384 + s * 8, smem + c * 16);
  }
  __syncthreads();                      // the ONLY barrier

  // ---- barrier-free k-loop: A in regs (1-tile prefetch), B from LDS ----
  const u16* abase = xb + (row0 + wr * 64 + l15) * 384 + lhi * 8;

  f32x4 acc[4][3];
  #pragma unroll
  for (int mt = 0; mt < 4; ++mt)
    #pragma unroll
    for (int nt = 0; nt < 3; ++nt) acc[mt][nt] = 0.0f;

  FragU a_cur[4], a_nxt[4];
  #pragma unroll
  for (int mt = 0; mt < 4; ++mt)
    a_cur[mt].u4 = *reinterpret_cast<const uint4*>(abase + mt * 6144);

  #pragma unroll
  for (int t = 0; t < 12; ++t){
    if (t < 11){
      #pragma unroll
      for (int mt = 0; mt < 4; ++mt)
        a_nxt[mt].u4 = *reinterpret_cast<const uint4*>(abase + mt * 6144 + (t + 1) * 32);
    }
    FragU bf[3];
    #pragma unroll
    for (int nt = 0; nt < 3; ++nt){
      int n = wc * 48 + nt * 16 + l15;
      bf[nt].bf = lds_frag(smem, 0, n, 768, t * 32 + lhi * 8);
    }
    #pragma unroll
    for (int mt = 0; mt < 4; ++mt)
      #pragma unroll
      for (int nt = 0; nt < 3; ++nt)
        acc[mt][nt] = __builtin_amdgcn_mfma_f32_16x16x32_bf16(a_cur[mt].bf, bf[nt].bf, acc[mt][nt], 0, 0, 0);
    #pragma unroll
    for (int mt = 0; mt < 4; ++mt) a_cur[mt] = a_nxt[mt];
  }

  if (sec < 2){
    // epilogue: bias + RoPE (+0.125 scale for q), bf16 store into out slots
    u16* o16 = (u16*)out;
    #pragma unroll
    for (int nt = 0; nt < 3; ++nt){
      const int ch = ny * 192 + wc * 48 + nt * 16 + l15;
      const float bias = bq[sec * 384 + ch];
      const int chh = ch & 63;
      const int p   = chh >> 1;
      const int m   = p & 15;
      const bool isR = (p < 16);
      const bool ev  = ((ch & 1) == 0);
      #pragma unroll
      for (int mt = 0; mt < 4; ++mt){
        #pragma unroll
        for (int r = 0; r < 4; ++r){
          const int i = wr * 64 + mt * 16 + lhi * 4 + r;
          float v = acc[mt][nt][r] + bias;
          float o = __shfl_xor(v, 1);
          int pos = isR ? r6 : (6 + (bcol * 128 + i + 6) % 12);
          float cc = tabc[pos * 16 + m], ssn = tabs[pos * 16 + m];
          float nv = ev ? (v * cc - o * ssn) : (o * ssn + v * cc);
          if (sec == 0) nv *= 0.125f;
          o16[(row0 + i) * 768 + sec * 384 + ch] = f2bf(nv);
        }
      }
    }
  } else {
    // v epilogue: bias, store into v_ws [win][h][chh][tok] (quads of 4 tokens)
    #pragma unroll
    for (int mt = 0; mt < 4; ++mt){
      const int ww2 = bcol * 128 + wr * 64 + mt * 16 + lhi * 4;  // first tok of quad
      const int rw  = (ww2 >= 6) ? ww2 - 6 : ww2 + 378;
      const int wj  = rw / 12;
      const int c0  = rw - wj * 12;            // in {2,6,10}
      const int tokb = r6 * 12;
      #pragma unroll
      for (int nt = 0; nt < 3; ++nt){
        const int ch  = ny * 192 + wc * 48 + nt * 16 + l15;
        const int h   = ch >> 6;
        const int chh = ch & 63;
        const float bv = bq[768 + ch];
        u32 lo = pkbf(acc[mt][nt][0] + bv, acc[mt][nt][1] + bv);
        u32 hi = pkbf(acc[mt][nt][2] + bv, acc[mt][nt][3] + bv);
        u16* basep = vws + ((size_t)(bwin + wj) * 6 + h) * 5120 + chh * 80;
        if (c0 != 10){
          *reinterpret_cast<u32*>(basep + tokb + c0)     = lo;
          *reinterpret_cast<u32*>(basep + tokb + c0 + 2) = hi;
        } else {
          *reinterpret_cast<u32*>(basep + tokb + 10) = lo;
          const int wj1 = (wj == 31) ? 0 : wj + 1;
          *reinterpret_cast<u32*>(vws + ((size_t)(bwin + wj1) * 6 + h) * 5120 + chh * 80 + tokb) = hi;
        }
      }
    }
  }
}

// ============ K3: per-window attention, fully LDS-staged via glds16 ============
// attnout -> axb [row][384] u16 (race-free vs proj N-split)
#define QH4 0
#define KH4 10240
#define VT4 20480
#define SMEM4 30720
__launch_bounds__(320, 5)
__global__ void win_attn4(const u16* __restrict__ vws,
                          float* __restrict__ out,
                          u16* __restrict__ axb)
{
  __shared__ __align__(16) unsigned char smem[SMEM4];
  const int tid  = threadIdx.x;
  const int wave = tid >> 6;
  const int lane = tid & 63;
  const int l15  = lane & 15;
  const int lhi  = lane >> 4;

  const int bid  = blockIdx.x;
  const int wgid = (bid & 7) * 256 + (bid >> 3);   // XCD swizzle (2048 = 8*256)
  const int bIdx = wgid >> 10;
  const int win  = wgid & 1023;
  const int wi   = win >> 5;
  const int wj   = win & 31;
  const bool maskWin = (wi == 31);

  auto rowof = [&](int t)->size_t {
    int r = t / 12, c = t - r * 12;
    int hh = wi * 6 + r + 3;  if (hh >= 192) hh -= 192;
    int ww = wj * 12 + c + 6; if (ww >= 384) ww -= 384;
    return ((size_t)bIdx * 192 + hh) * 384 + ww;
  };
  const int qtok = wave * 16 + l15;     // 0..79
  const bool tv = (qtok < 72);
  const size_t qrow = rowof(tv ? qtok : 71);

  const u16* o16c = (const u16*)out;
  const u16* vsl = vws + (size_t)win * 30720 + (size_t)bIdx * 31457280; // win*6*5120

  float sv[5][4];
  #pragma unroll
  for (int a2 = 0; a2 < 5; ++a2)
    #pragma unroll
    for (int b2 = 0; b2 < 4; ++b2) sv[a2][b2] = 0.0f;

  for (int h = 0; h < 6; ++h){
    // ---- stage q,k (swizzled src) and v (linear) : 1920 glds16 chunks ----
    #pragma unroll
    for (int it = 0; it < 2; ++it){
      int c = it * 320 + tid;           // 0..639
      int t = c >> 3, p = c & 7;
      size_t row = rowof(t < 72 ? t : 71);
      int s = (p ^ (t & 7)) << 3;
      glds16(o16c + row * 768 + h * 64 + s,       smem + QH4 + c * 16);
      glds16(o16c + row * 768 + 384 + h * 64 + s, smem + KH4 + c * 16);
      glds16(vsl + (size_t)h * 5120 + c * 8,      smem + VT4 + c * 16);
    }
    __syncthreads();                    // stage visible

    // ---- QK^T: C[i=k][j=q] ----
    f32x4 pf[5];
    #pragma unroll
    for (int nt = 0; nt < 5; ++nt) pf[nt] = 0.0f;
    __builtin_amdgcn_s_setprio(1);
    #pragma unroll
    for (int ks = 0; ks < 2; ++ks){
      const int kEl = ks * 32 + lhi * 8;
      bf16x8 qf = lds_frag(smem, QH4, qtok, 128, kEl);
      #pragma unroll
      for (int nt = 0; nt < 5; ++nt){
        bf16x8 kf = lds_frag(smem, KH4, nt * 16 + l15, 128, kEl);
        pf[nt] = __builtin_amdgcn_mfma_f32_16x16x32_bf16(kf, qf, pf[nt], 0, 0, 0);
      }
    }
    __builtin_amdgcn_s_setprio(0);

    // ---- mask + softmax over k ----
    float mx = -1e30f;
    #pragma unroll
    for (int nt = 0; nt < 5; ++nt)
      #pragma unroll
      for (int r = 0; r < 4; ++r){
        const int kk2 = nt * 16 + lhi * 4 + r;
        bool valid = (kk2 < 72) && (!maskWin || ((kk2 < 36) == (qtok < 36)));
        float val = valid ? pf[nt][r] : -1e30f;
        pf[nt][r] = val;
        mx = fmaxf(mx, val);
      }
    mx = fmaxf(mx, __shfl_xor(mx, 16));
    mx = fmaxf(mx, __shfl_xor(mx, 32));
    float sm = 0.0f;
    #pragma unroll
    for (int nt = 0; nt < 5; ++nt)
      #pragma unroll
      for (int r = 0; r < 4; ++r){
        float e = __expf(pf[nt][r] - mx);
        pf[nt][r] = e; sm += e;
      }
    sm += __shfl_xor(sm, 16);
    sm += __shfl_xor(sm, 32);
    const float inv = 1.0f / sm;
    u32 pp[5][2];                       // packed bf16 pairs: P[k..k+1][q=l15]
    #pragma unroll
    for (int nt = 0; nt < 5; ++nt){
      float p0 = pf[nt][0] * inv, p1 = pf[nt][1] * inv;
      float p2 = pf[nt][2] * inv, p3 = pf[nt][3] * inv;
      sv[nt][0] += p0; sv[nt][1] += p1; sv[nt][2] += p2; sv[nt][3] += p3;
      pp[nt][0] = pkbf(p0, p1);
      pp[nt][1] = pkbf(p2, p3);
    }

    // ---- PV: C[i=ch][j=q]; B-frags of P built by shfl (no LDS, no barrier) ----
    f32x4 oacc[4];
    #pragma unroll
    for (int nt = 0; nt < 4; ++nt) oacc[nt] = 0.0f;
    #pragma unroll
    for (int ks = 0; ks < 3; ++ks){
      FragU pb;
      u32 w[4];
      #pragma unroll
      for (int w_ = 0; w_ < 4; ++w_){
        int srcLane = l15 + 16 * ((lane >> 4 & 1) * 2 + (w_ >> 1));
        u32 c0 = __shfl(pp[ks * 2][w_ & 1], srcLane);
        u32 c1 = (ks * 2 + 1 < 5) ? __shfl(pp[ks * 2 + 1][w_ & 1], srcLane) : 0u;
        w[w_] = (lhi & 2) ? c1 : c0;
      }
      pb.u4.x = w[0]; pb.u4.y = w[1]; pb.u4.z = w[2]; pb.u4.w = w[3];
      const int kEl = ks * 32 + lhi * 8;
      __builtin_amdgcn_s_setprio(1);
      #pragma unroll
      for (int nt = 0; nt < 4; ++nt){
        FragU vf;
        vf.u4 = *reinterpret_cast<const uint4*>(smem + VT4 + (nt * 16 + l15) * 160 + kEl * 2);
        oacc[nt] = __builtin_amdgcn_mfma_f32_16x16x32_bf16(vf.bf, pb.bf, oacc[nt], 0, 0, 0);
      }
      __builtin_amdgcn_s_setprio(0);
    }
    if (tv){
      u16* ao = axb + qrow * 384 + h * 64;
      #pragma unroll
      for (int nt = 0; nt < 4; ++nt){
        uint2 pk;
        pk.x = pkbf(oacc[nt][0], oacc[nt][1]);
        pk.y = pkbf(oacc[nt][2], oacc[nt][3]);
        *reinterpret_cast<uint2*>(ao + nt * 16 + lhi * 4) = pk;
      }
    }
    __syncthreads();                    // all LDS reads done before next stage
  } // heads

  // ---- save_attn = mean over heads: so[q*72 + k] ----
  if (tv){
    float* so = out + 56623104ull + (size_t)wgid * 5184 + (size_t)qtok * 72;
    const float c6 = 1.0f / 6.0f;
    #pragma unroll
    for (int nt = 0; nt < 4; ++nt){
      float4 v4; v4.x = sv[nt][0]*c6; v4.y = sv[nt][1]*c6; v4.z = sv[nt][2]*c6; v4.w = sv[nt][3]*c6;
      *reinterpret_cast<float4*>(so + nt * 16 + lhi * 4) = v4;
    }
    if (lhi < 2){
      float4 v4; v4.x = sv[4][0]*c6; v4.y = sv[4][1]*c6; v4.z = sv[4][2]*c6; v4.w = sv[4][3]*c6;
      *reinterpret_cast<float4*>(so + 64 + lhi * 4) = v4;
    }
  }
}

// ======================================================================
// K4 v8: out-projection GEMM, same full-B-resident barrier-free structure.
// A frags from axb [row][384] u16 (no aliasing with f32 out). Grid 2304
// flat with XCD co-location of the 2 ny-variants per row-block.
// ======================================================================
__launch_bounds__(512, 2)
__global__ void proj_gemm3(const u16* __restrict__ axb,
                           const u16* __restrict__ wpb, const float* __restrict__ bp,
                           float* __restrict__ out)
{
  __shared__ __align__(16) unsigned char smem[147456];
  const int tid  = threadIdx.x;
  const int wave = tid >> 6;
  const int lane = tid & 63;
  const int l15  = lane & 15;
  const int lhi  = lane >> 4;
  const int wr   = wave >> 2;
  const int wc   = wave & 3;

  const int bid = blockIdx.x;           // 0..2303
  const int l   = (bid & 7) * 288 + (bid >> 3);
  const size_t row0 = (size_t)(l >> 1) * 128;
  const int ny  = l & 1;

  // ---- stage B panel [192][384] once ----
  const u16* bsec = wpb + (size_t)(ny * 192) * 384;
  #pragma unroll
  for (int it = 0; it < 18; ++it){
    int c   = it * 512 + tid;
    int row = c / 48;
    int p   = c - row * 48;
    int s   = (p & ~7) | ((p & 7) ^ (row & 7));
    glds16(bsec + (size_t)row * 384 + s * 8, smem + c * 16);
  }
  __syncthreads();

  const u16* abase = axb + (row0 + wr * 64 + l15) * 384 + lhi * 8;

  f32x4 acc[4][3];
  #pragma unroll
  for (int mt = 0; mt < 4; ++mt)
    #pragma unroll
    for (int nt = 0; nt < 3; ++nt) acc[mt][nt] = 0.0f;

  FragU a_cur[4], a_nxt[4];
  #pragma unroll
  for (int mt = 0; mt < 4; ++mt)
    a_cur[mt].u4 = *reinterpret_cast<const uint4*>(abase + mt * 6144);

  #pragma unroll
  for (int t = 0; t < 12; ++t){
    if (t < 11){
      #pragma unroll
      for (int mt = 0; mt < 4; ++mt)
        a_nxt[mt].u4 = *reinterpret_cast<const uint4*>(abase + mt * 6144 + (t + 1) * 32);
    }
    FragU bf[3];
    #pragma unroll
    for (int nt = 0; nt < 3; ++nt){
      int n = wc * 48 + nt * 16 + l15;
      bf[nt].bf = lds_frag(smem, 0, n, 768, t * 32 + lhi * 8);
    }
    #pragma unroll
    for (int mt = 0; mt < 4; ++mt)
      #pragma unroll
      for (int nt = 0; nt < 3; ++nt)
        acc[mt][nt] = __builtin_amdgcn_mfma_f32_16x16x32_bf16(a_cur[mt].bf, bf[nt].bf, acc[mt][nt], 0, 0, 0);
    #pragma unroll
    for (int mt = 0; mt < 4; ++mt) a_cur[mt] = a_nxt[mt];
  }

  float bpv[3];
  #pragma unroll
  for (int nt = 0; nt < 3; ++nt) bpv[nt] = bp[ny * 192 + wc * 48 + nt * 16 + l15];
  #pragma unroll
  for (int mt = 0; mt < 4; ++mt)
    #pragma unroll
    for (int nt = 0; nt < 3; ++nt){
      const int ch = ny * 192 + wc * 48 + nt * 16 + l15;
      #pragma unroll
      for (int r = 0; r < 4; ++r){
        size_t grow = row0 + wr * 64 + mt * 16 + lhi * 4 + r;
        out[grow * 384 + ch] = acc[mt][nt][r] + bpv[nt];
      }
    }
}

extern "C" void kernel_launch(void* const* d_in, const int* in_sizes, int n_in,
                              void* d_out, int out_size, void* d_ws, size_t ws_size,
                              hipStream_t stream)
{
  const float* x  = (const float*)d_in[0];
  const float* wq = (const float*)d_in[1];
  const float* bq = (const float*)d_in[2];
  const float* wp = (const float*)d_in[3];
  const float* bp = (const float*)d_in[4];
  float* out = (float*)d_out;

  u16* wqb = (u16*)d_ws;                              // 442368 bf16
  u16* wpb = (u16*)((char*)d_ws + 442368 * 2);        // 147456 bf16
  u16* vws = (u16*)((char*)d_ws + 1179648);           // 2048*6*5120 bf16 (125.8 MB)
  u16* xb  = (u16*)((char*)d_ws + 127008768);         // 147456*384 bf16 (113.2 MB)
  // ws_size >= 240254976 confirmed by rounds 5/7 counters (big2 path ran:
  // FETCH_SIZE halved when prep_x+xb were introduced).

  prep_weights<<<1728, 256, 0, stream>>>(wq, wp, wqb, wpb);
  prep_x<<<27648, 256, 0, stream>>>(x, xb);
  qkv_gemm3<<<6912, 512, 0, stream>>>(xb, wqb, bq, out, vws);
  win_attn4<<<2048, 320, 0, stream>>>(vws, out, xb);   // attnout -> xb (dead after qkv)
  proj_gemm3<<<2304, 512, 0, stream>>>(xb, wpb, bp, out);
}

// Round 9
// 820.012 us; speedup vs baseline: 1.1569x; 1.1569x over previous
//
#include <hip/hip_runtime.h>

typedef __attribute__((ext_vector_type(8))) __bf16 bf16x8;
typedef __attribute__((ext_vector_type(4))) float f32x4;
typedef unsigned short u16;
typedef unsigned int u32;

__device__ __forceinline__ u16 f2bf(float x){
  u32 u = __float_as_uint(x);
  return (u16)((u + 0x7fffu + ((u >> 16) & 1u)) >> 16);
}
__device__ __forceinline__ u32 pkbf(float lo, float hi){
  u32 r; asm("v_cvt_pk_bf16_f32 %0, %1, %2" : "=v"(r) : "v"(lo), "v"(hi)); return r;
}

union FragU { uint4 u4; bf16x8 bf; };

__device__ __forceinline__ bf16x8 lds_frag(const unsigned char* smem, int off, int row, int strideB, int kElem){
  int byte = (row * strideB + kElem * 2) ^ ((row & 7) << 4);
  FragU f; f.u4 = *reinterpret_cast<const uint4*>(smem + off + byte);
  return f.bf;
}

typedef __attribute__((address_space(3))) unsigned char lds_u8;
typedef __attribute__((address_space(1))) const unsigned char g_u8;
__device__ __forceinline__ void glds16(const void* g, void* l){
  __builtin_amdgcn_global_load_lds((g_u8*)g, (lds_u8*)l, 16, 0, 0);
}

__global__ void prep_weights(const float* __restrict__ wq, const float* __restrict__ wp,
                             u16* __restrict__ wqb, u16* __restrict__ wpb){
  int i = blockIdx.x * 256 + threadIdx.x;
  wqb[i] = f2bf(wq[i]);              // grid sized exactly for 442368
  if (i < 147456) wpb[i] = f2bf(wp[i]);
}

// x f32 -> bf16, linear [147456][384]
__global__ void prep_x(const float* __restrict__ x, u16* __restrict__ xb){
  size_t i = ((size_t)blockIdx.x * 256 + threadIdx.x) * 8;
  float4 f0 = *reinterpret_cast<const float4*>(x + i);
  float4 f1 = *reinterpret_cast<const float4*>(x + i + 4);
  uint4 q;
  q.x = pkbf(f0.x, f0.y); q.y = pkbf(f0.z, f0.w);
  q.z = pkbf(f1.x, f1.y); q.w = pkbf(f1.z, f1.w);
  *reinterpret_cast<uint4*>(xb + i) = q;
}

// ======================================================================
// K2 v9: qkv GEMM (r5 structure: M=128, N=384, BK=64, glds16 A+B, barrier
// per k-tile) with: (a) flat XCD-co-located grid -- the 3 secs of one bx
// run on the same XCD so A is fetched from HBM once; (b) v epilogue writes
// ROW-MAJOR vws2[win][72tok][384ch] -- every v-row = 6 fully-written 64B
// lines (no scatter, no partial-line HBM writes).
// ======================================================================
#define QA_OFF 0        // [128][64] bf16 swz : 16384
#define QB_OFF 16384    // [384][64] bf16 swz : 49152 -> 65536
#define QTC    65536    // 288 f32
#define QTS    66688    // 288 f32 -> 67840
__launch_bounds__(512, 2)
__global__ void qkv_gemm4(const u16* __restrict__ xb,
                          const u16* __restrict__ wqb,
                          const float* __restrict__ bq, float* __restrict__ out,
                          u16* __restrict__ vws2)
{
  __shared__ __align__(16) unsigned char smem[67840];
  const int tid  = threadIdx.x;
  const int wave = tid >> 6;
  const int lane = tid & 63;
  const int l15  = lane & 15;
  const int lhi  = lane >> 4;
  const int wr   = wave >> 2;           // 0..1 : 64-row half
  const int wc   = wave & 3;            // 0..3 : 96-col quarter

  // XCD co-location: blocks with same bid%8 land on one XCD; give them
  // consecutive l so the 3 secs of each bx share the A panel in L2.
  const int bid = blockIdx.x;           // 0..3455 (= 8 * 432)
  const int l   = (bid & 7) * 432 + (bid >> 3);
  const int bx  = l / 3;                // 0..1151
  const int sec = l - bx * 3;           // 0=q,1=k,2=v

  const size_t row0 = (size_t)bx * 128;
  const int a    = bx / 3;              // global image-row index (0..383)
  const int bcol = bx - 3 * a;
  const int bIm  = a / 192;
  const int hh   = a % 192;
  const int rh   = (hh >= 3) ? hh - 3 : hh + 189;   // rolled row
  const int wi   = rh / 6;
  const int r6   = rh - wi * 6;                      // window-row of all tokens
  const int bwin = bIm * 1024 + wi * 32;

  float* tabc = reinterpret_cast<float*>(smem + QTC);
  float* tabs = reinterpret_cast<float*>(smem + QTS);
  if (tid < 288){
    int pos = tid >> 4, m = tid & 15;
    float pv = (pos < 6) ? (float)pos : (float)(pos - 6);
    float ang = pv * __expf(-(float)m * 0.5756462732485114f); // 10000^(-m/16)
    tabc[tid] = cosf(ang);
    tabs[tid] = sinf(ang);
  }

  f32x4 acc[4][6];
  #pragma unroll
  for (int mt = 0; mt < 4; ++mt)
    #pragma unroll
    for (int nt = 0; nt < 6; ++nt) acc[mt][nt] = 0.0f;

  for (int kk = 0; kk < 6; ++kk){
    // stage A: [128][64] via async global->LDS from bf16 xb (swizzled src)
    #pragma unroll
    for (int it = 0; it < 2; ++it){
      int c = it * 512 + tid;
      int rrow = c >> 3, p = c & 7;
      int s = p ^ (rrow & 7);
      glds16(xb + (row0 + rrow) * 384 + kk * 64 + s * 8,
             smem + QA_OFF + c * 16);
    }
    // stage B: [384][64] via async global->LDS
    #pragma unroll
    for (int it = 0; it < 6; ++it){
      int c = it * 512 + tid;
      int n = c >> 3, p = c & 7;
      int s = p ^ (n & 7);
      glds16(wqb + (size_t)(sec * 384 + n) * 384 + kk * 64 + s * 8,
             smem + QB_OFF + c * 16);
    }
    __syncthreads();
    #pragma unroll
    for (int ks = 0; ks < 2; ++ks){
      const int kEl = ks * 32 + lhi * 8;
      bf16x8 af[4], bfr[6];
      #pragma unroll
      for (int mt = 0; mt < 4; ++mt)
        af[mt] = lds_frag(smem, QA_OFF, wr * 64 + mt * 16 + l15, 128, kEl);
      #pragma unroll
      for (int nt = 0; nt < 6; ++nt)
        bfr[nt] = lds_frag(smem, QB_OFF, wc * 96 + nt * 16 + l15, 128, kEl);
      #pragma unroll
      for (int mt = 0; mt < 4; ++mt)
        #pragma unroll
        for (int nt = 0; nt < 6; ++nt)
          acc[mt][nt] = __builtin_amdgcn_mfma_f32_16x16x32_bf16(af[mt], bfr[nt], acc[mt][nt], 0, 0, 0);
    }
    __syncthreads();
  }

  if (sec < 2){
    // epilogue: bias + RoPE (+0.125 scale for q), bf16 store into out slots
    u16* o16 = (u16*)out;
    #pragma unroll
    for (int nt = 0; nt < 6; ++nt){
      const int ch = wc * 96 + nt * 16 + l15;
      const float bias = bq[sec * 384 + ch];
      const int chh = ch & 63;
      const int p   = chh >> 1;
      const int m   = p & 15;
      const bool isR = (p < 16);
      const bool ev  = ((ch & 1) == 0);
      #pragma unroll
      for (int mt = 0; mt < 4; ++mt){
        #pragma unroll
        for (int r = 0; r < 4; ++r){
          const int i = wr * 64 + mt * 16 + lhi * 4 + r;
          float v = acc[mt][nt][r] + bias;
          float o = __shfl_xor(v, 1);
          int pos = isR ? r6 : (6 + (bcol * 128 + i + 6) % 12);
          float cc = tabc[pos * 16 + m], ssn = tabs[pos * 16 + m];
          float nv = ev ? (v * cc - o * ssn) : (o * ssn + v * cc);
          if (sec == 0) nv *= 0.125f;
          o16[(row0 + i) * 768 + sec * 384 + ch] = f2bf(nv);
        }
      }
    }
  } else {
    // v epilogue: bias + ROW-MAJOR store into vws2[(bwin+wj)*72 + tok][384]
    float bias[6];
    #pragma unroll
    for (int nt = 0; nt < 6; ++nt) bias[nt] = bq[768 + wc * 96 + nt * 16 + l15];
    #pragma unroll
    for (int mt = 0; mt < 4; ++mt){
      #pragma unroll
      for (int r = 0; r < 4; ++r){
        const int i   = wr * 64 + mt * 16 + lhi * 4 + r;
        const int ww2 = bcol * 128 + i;
        const int rw  = (ww2 >= 6) ? ww2 - 6 : ww2 + 378;
        const int wj  = rw / 12;
        const int cc  = rw - wj * 12;
        u16* vrow = vws2 + ((size_t)(bwin + wj) * 72 + r6 * 12 + cc) * 384 + wc * 96;
        #pragma unroll
        for (int nt = 0; nt < 6; ++nt)
          vrow[nt * 16 + l15] = f2bf(acc[mt][nt][r] + bias[nt]);
      }
    }
  }
}

// ============ K3 v9: per-window attention ============
// q,k LDS-staged via glds16 (as before). V^T built in-kernel: per head,
// 2 uint4 loads from row-major vws2 + 16 ds_write_b16 into XOR-swizzled
// VT [64ch][80tok] (+256B zero guard). attnout -> axb [row][384].
#define QH4 0
#define KH4 10240
#define VT4 20480      // 64*160 + 256 guard = 10496 -> SMEM 30976
#define SMEM4 30976
__launch_bounds__(320, 5)
__global__ void win_attn5(const u16* __restrict__ vws2,
                          float* __restrict__ out,
                          u16* __restrict__ axb)
{
  __shared__ __align__(16) unsigned char smem[SMEM4];
  const int tid  = threadIdx.x;
  const int wave = tid >> 6;
  const int lane = tid & 63;
  const int l15  = lane & 15;
  const int lhi  = lane >> 4;

  const int bid  = blockIdx.x;
  const int wgid = (bid & 7) * 256 + (bid >> 3);   // XCD swizzle (2048 = 8*256)
  const int bIdx = wgid >> 10;
  const int win  = wgid & 1023;
  const int wi   = win >> 5;
  const int wj   = win & 31;
  const bool maskWin = (wi == 31);

  auto rowof = [&](int t)->size_t {
    int r = t / 12, c = t - r * 12;
    int hh = wi * 6 + r + 3;  if (hh >= 192) hh -= 192;
    int ww = wj * 12 + c + 6; if (ww >= 384) ww -= 384;
    return ((size_t)bIdx * 192 + hh) * 384 + ww;
  };
  const int qtok = wave * 16 + l15;     // 0..79
  const bool tv = (qtok < 72);
  const size_t qrow = rowof(tv ? qtok : 71);

  const u16* o16c = (const u16*)out;
  const u16* vbase = vws2 + ((size_t)bIdx * 1024 + win) * 72 * 384;

  // zero the VT guard region (toks >=80 reads land here; must be 0, not 0xAA)
  if (tid < 64) *reinterpret_cast<u32*>(smem + VT4 + 10240 + tid * 4) = 0u;

  float sv[5][4];
  #pragma unroll
  for (int a2 = 0; a2 < 5; ++a2)
    #pragma unroll
    for (int b2 = 0; b2 < 4; ++b2) sv[a2][b2] = 0.0f;

  for (int h = 0; h < 6; ++h){
    // ---- stage q,k via glds16 (swizzled src) ----
    #pragma unroll
    for (int it = 0; it < 2; ++it){
      int c = it * 320 + tid;           // 0..639
      int t = c >> 3, p = c & 7;
      size_t row = rowof(t < 72 ? t : 71);
      int s = (p ^ (t & 7)) << 3;
      glds16(o16c + row * 768 + h * 64 + s,       smem + QH4 + c * 16);
      glds16(o16c + row * 768 + 384 + h * 64 + s, smem + KH4 + c * 16);
    }
    // ---- build V^T: load 8 ch of one tok (16B, L2-hot), transpose-write ----
    // write byte = (ch*160 + tok*2) ^ (cg<<4), cg = ch>>3  -> conflict-free
    #pragma unroll
    for (int it = 0; it < 2; ++it){
      int c   = it * 320 + tid;         // 0..639
      int tok = c >> 3, cg = c & 7;
      uint4 vv; vv.x = 0; vv.y = 0; vv.z = 0; vv.w = 0;
      if (tok < 72)
        vv = *reinterpret_cast<const uint4*>(vbase + (size_t)tok * 384 + h * 64 + cg * 8);
      const int rowb = cg * 8 * 160;
      const int sw   = cg << 4;
      #pragma unroll
      for (int j = 0; j < 8; ++j){
        u32 word = (j < 2) ? vv.x : (j < 4) ? vv.y : (j < 6) ? vv.z : vv.w;
        u16 val  = (j & 1) ? (u16)(word >> 16) : (u16)(word & 0xffffu);
        int byte = (rowb + j * 160 + tok * 2) ^ sw;
        *reinterpret_cast<u16*>(smem + VT4 + byte) = val;
      }
    }
    __syncthreads();                    // stage + transpose visible

    // ---- QK^T: C[i=k][j=q] ----
    f32x4 pf[5];
    #pragma unroll
    for (int nt = 0; nt < 5; ++nt) pf[nt] = 0.0f;
    __builtin_amdgcn_s_setprio(1);
    #pragma unroll
    for (int ks = 0; ks < 2; ++ks){
      const int kEl = ks * 32 + lhi * 8;
      bf16x8 qf = lds_frag(smem, QH4, qtok, 128, kEl);
      #pragma unroll
      for (int nt = 0; nt < 5; ++nt){
        bf16x8 kf = lds_frag(smem, KH4, nt * 16 + l15, 128, kEl);
        pf[nt] = __builtin_amdgcn_mfma_f32_16x16x32_bf16(kf, qf, pf[nt], 0, 0, 0);
      }
    }
    __builtin_amdgcn_s_setprio(0);

    // ---- mask + softmax over k ----
    float mx = -1e30f;
    #pragma unroll
    for (int nt = 0; nt < 5; ++nt)
      #pragma unroll
      for (int r = 0; r < 4; ++r){
        const int kk2 = nt * 16 + lhi * 4 + r;
        bool valid = (kk2 < 72) && (!maskWin || ((kk2 < 36) == (qtok < 36)));
        float val = valid ? pf[nt][r] : -1e30f;
        pf[nt][r] = val;
        mx = fmaxf(mx, val);
      }
    mx = fmaxf(mx, __shfl_xor(mx, 16));
    mx = fmaxf(mx, __shfl_xor(mx, 32));
    float sm = 0.0f;
    #pragma unroll
    for (int nt = 0; nt < 5; ++nt)
      #pragma unroll
      for (int r = 0; r < 4; ++r){
        float e = __expf(pf[nt][r] - mx);
        pf[nt][r] = e; sm += e;
      }
    sm += __shfl_xor(sm, 16);
    sm += __shfl_xor(sm, 32);
    const float inv = 1.0f / sm;
    u32 pp[5][2];                       // packed bf16 pairs: P[k..k+1][q=l15]
    #pragma unroll
    for (int nt = 0; nt < 5; ++nt){
      float p0 = pf[nt][0] * inv, p1 = pf[nt][1] * inv;
      float p2 = pf[nt][2] * inv, p3 = pf[nt][3] * inv;
      sv[nt][0] += p0; sv[nt][1] += p1; sv[nt][2] += p2; sv[nt][3] += p3;
      pp[nt][0] = pkbf(p0, p1);
      pp[nt][1] = pkbf(p2, p3);
    }

    // ---- PV: C[i=ch][j=q]; P B-frags via shfl; V^T from swizzled VT ----
    f32x4 oacc[4];
    #pragma unroll
    for (int nt = 0; nt < 4; ++nt) oacc[nt] = 0.0f;
    #pragma unroll
    for (int ks = 0; ks < 3; ++ks){
      FragU pb;
      u32 w[4];
      #pragma unroll
      for (int w_ = 0; w_ < 4; ++w_){
        int srcLane = l15 + 16 * ((lane >> 4 & 1) * 2 + (w_ >> 1));
        u32 c0 = __shfl(pp[ks * 2][w_ & 1], srcLane);
        u32 c1 = (ks * 2 + 1 < 5) ? __shfl(pp[ks * 2 + 1][w_ & 1], srcLane) : 0u;
        w[w_] = (lhi & 2) ? c1 : c0;
      }
      pb.u4.x = w[0]; pb.u4.y = w[1]; pb.u4.z = w[2]; pb.u4.w = w[3];
      const int kEl = ks * 32 + lhi * 8;
      __builtin_amdgcn_s_setprio(1);
      #pragma unroll
      for (int nt = 0; nt < 4; ++nt){
        const int chv = nt * 16 + l15;
        const int vbyte = (chv * 160 + kEl * 2) ^ (((chv >> 3) & 7) << 4);
        FragU vf;
        vf.u4 = *reinterpret_cast<const uint4*>(smem + VT4 + vbyte);
        oacc[nt] = __builtin_amdgcn_mfma_f32_16x16x32_bf16(vf.bf, pb.bf, oacc[nt], 0, 0, 0);
      }
      __builtin_amdgcn_s_setprio(0);
    }
    if (tv){
      u16* ao = axb + qrow * 384 + h * 64;
      #pragma unroll
      for (int nt = 0; nt < 4; ++nt){
        uint2 pk;
        pk.x = pkbf(oacc[nt][0], oacc[nt][1]);
        pk.y = pkbf(oacc[nt][2], oacc[nt][3]);
        *reinterpret_cast<uint2*>(ao + nt * 16 + lhi * 4) = pk;
      }
    }
    __syncthreads();                    // all LDS reads done before next stage
  } // heads

  // ---- save_attn = mean over heads: so[q*72 + k] ----
  if (tv){
    float* so = out + 56623104ull + (size_t)wgid * 5184 + (size_t)qtok * 72;
    const float c6 = 1.0f / 6.0f;
    #pragma unroll
    for (int nt = 0; nt < 4; ++nt){
      float4 v4; v4.x = sv[nt][0]*c6; v4.y = sv[nt][1]*c6; v4.z = sv[nt][2]*c6; v4.w = sv[nt][3]*c6;
      *reinterpret_cast<float4*>(so + nt * 16 + lhi * 4) = v4;
    }
    if (lhi < 2){
      float4 v4; v4.x = sv[4][0]*c6; v4.y = sv[4][1]*c6; v4.z = sv[4][2]*c6; v4.w = sv[4][3]*c6;
      *reinterpret_cast<float4*>(so + 64 + lhi * 4) = v4;
    }
  }
}

// ======================================================================
// K4: out-projection GEMM (r7 version, proven): tile M=128 x N=192, BK=32,
// 2-phase dbuf B, A frags direct from axb [row][384] u16. grid (1152, 2).
// ======================================================================
#define B6STR 12288
__launch_bounds__(512, 4)
__global__ void proj_gemm2(const u16* __restrict__ axb,
                           const u16* __restrict__ wpb, const float* __restrict__ bp,
                           float* __restrict__ out)
{
  __shared__ __align__(16) unsigned char smem[24576];
  const int tid  = threadIdx.x;
  const int wave = tid >> 6;
  const int lane = tid & 63;
  const int l15  = lane & 15;
  const int lhi  = lane >> 4;
  const int wr   = wave >> 2;
  const int wc   = wave & 3;
  const size_t row0 = (size_t)blockIdx.x * 128;
  const int ny   = blockIdx.y;

  const u16* bsec = wpb + (size_t)(ny * 192) * 384;
  auto stageB = [&](int t, int bufOff){
    {
      int c = tid, row = c >> 2, ccd = c & 3;
      int ccs = ccd ^ ((row >> 1) & 3);
      glds16(bsec + (size_t)row * 384 + t * 32 + ccs * 8, smem + bufOff + c * 16);
    }
    if (tid < 256){
      int c = 512 + tid, row = c >> 2, ccd = c & 3;
      int ccs = ccd ^ ((row >> 1) & 3);
      glds16(bsec + (size_t)row * 384 + t * 32 + ccs * 8, smem + bufOff + c * 16);
    }
  };

  const u16* abase = axb + (row0 + wr * 64 + l15) * 384 + lhi * 8;

  f32x4 acc[4][3];
  #pragma unroll
  for (int mt = 0; mt < 4; ++mt)
    #pragma unroll
    for (int nt = 0; nt < 3; ++nt) acc[mt][nt] = 0.0f;

  FragU a_cur[4], a_nxt[4];
  #pragma unroll
  for (int mt = 0; mt < 4; ++mt)
    a_cur[mt].u4 = *reinterpret_cast<const uint4*>(abase + mt * 6144);
  stageB(0, 0);
  __syncthreads();

  int buf = 0;
  for (int t = 0; t < 12; ++t){
    if (t < 11){
      stageB(t + 1, buf ^ B6STR);
      #pragma unroll
      for (int mt = 0; mt < 4; ++mt)
        a_nxt[mt].u4 = *reinterpret_cast<const uint4*>(abase + mt * 6144 + (t + 1) * 32);
    }
    FragU bfr[3];
    #pragma unroll
    for (int nt = 0; nt < 3; ++nt){
      int rown = wc * 48 + nt * 16 + l15;
      int byte = buf + rown * 64 + ((lhi ^ ((rown >> 1) & 3)) << 4);
      bfr[nt].u4 = *reinterpret_cast<const uint4*>(smem + byte);
    }
    #pragma unroll
    for (int mt = 0; mt < 4; ++mt)
      #pragma unroll
      for (int nt = 0; nt < 3; ++nt)
        acc[mt][nt] = __builtin_amdgcn_mfma_f32_16x16x32_bf16(a_cur[mt].bf, bfr[nt].bf, acc[mt][nt], 0, 0, 0);
    __syncthreads();
    #pragma unroll
    for (int mt = 0; mt < 4; ++mt) a_cur[mt] = a_nxt[mt];
    buf ^= B6STR;
  }

  float bpv[3];
  #pragma unroll
  for (int nt = 0; nt < 3; ++nt) bpv[nt] = bp[ny * 192 + wc * 48 + nt * 16 + l15];
  #pragma unroll
  for (int mt = 0; mt < 4; ++mt)
    #pragma unroll
    for (int nt = 0; nt < 3; ++nt){
      const int ch = ny * 192 + wc * 48 + nt * 16 + l15;
      #pragma unroll
      for (int r = 0; r < 4; ++r){
        size_t grow = row0 + wr * 64 + mt * 16 + lhi * 4 + r;
        out[grow * 384 + ch] = acc[mt][nt][r] + bpv[nt];
      }
    }
}

extern "C" void kernel_launch(void* const* d_in, const int* in_sizes, int n_in,
                              void* d_out, int out_size, void* d_ws, size_t ws_size,
                              hipStream_t stream)
{
  const float* x  = (const float*)d_in[0];
  const float* wq = (const float*)d_in[1];
  const float* bq = (const float*)d_in[2];
  const float* wp = (const float*)d_in[3];
  const float* bp = (const float*)d_in[4];
  float* out = (float*)d_out;

  u16* wqb  = (u16*)d_ws;                              // 442368 bf16
  u16* wpb  = (u16*)((char*)d_ws + 442368 * 2);        // 147456 bf16
  u16* vws2 = (u16*)((char*)d_ws + 1179648);           // 2048*72*384 bf16 (113.2 MB)
  u16* xb   = (u16*)((char*)d_ws + 127008768);         // 147456*384 bf16 (113.2 MB)
  // ws_size >= 240254976 confirmed by rounds 5/7 counters (big2 path ran).

  prep_weights<<<1728, 256, 0, stream>>>(wq, wp, wqb, wpb);
  prep_x<<<27648, 256, 0, stream>>>(x, xb);
  qkv_gemm4<<<3456, 512, 0, stream>>>(xb, wqb, bq, out, vws2);
  win_attn5<<<2048, 320, 0, stream>>>(vws2, out, xb);  // attnout -> xb (dead after qkv)
  proj_gemm2<<<dim3(1152, 2), 512, 0, stream>>>(xb, wpb, bp, out);
}

// Round 11
// 636.328 us; speedup vs baseline: 1.4909x; 1.2887x over previous
//
#include <hip/hip_runtime.h>

typedef __attribute__((ext_vector_type(8))) __bf16 bf16x8;
typedef __attribute__((ext_vector_type(4))) float f32x4;
typedef unsigned short u16;
typedef unsigned int u32;

__device__ __forceinline__ u16 f2bf(float x){
  u32 u = __float_as_uint(x);
  return (u16)((u + 0x7fffu + ((u >> 16) & 1u)) >> 16);
}
__device__ __forceinline__ u32 pkbf(float lo, float hi){
  u32 r; asm("v_cvt_pk_bf16_f32 %0, %1, %2" : "=v"(r) : "v"(lo), "v"(hi)); return r;
}

union FragU { uint4 u4; bf16x8 bf; };

__device__ __forceinline__ bf16x8 lds_frag(const unsigned char* smem, int off, int row, int strideB, int kElem){
  int byte = (row * strideB + kElem * 2) ^ ((row & 7) << 4);
  FragU f; f.u4 = *reinterpret_cast<const uint4*>(smem + off + byte);
  return f.bf;
}

typedef __attribute__((address_space(3))) unsigned char lds_u8;
typedef __attribute__((address_space(1))) const unsigned char g_u8;
__device__ __forceinline__ void glds16(const void* g, void* l){
  __builtin_amdgcn_global_load_lds((g_u8*)g, (lds_u8*)l, 16, 0, 0);
}

__global__ void prep_weights(const float* __restrict__ wq, const float* __restrict__ wp,
                             u16* __restrict__ wqb, u16* __restrict__ wpb){
  int i = blockIdx.x * 256 + threadIdx.x;
  wqb[i] = f2bf(wq[i]);              // grid sized exactly for 442368
  if (i < 147456) wpb[i] = f2bf(wp[i]);
}

// x f32 -> bf16, linear [147456][384]
__global__ void prep_x(const float* __restrict__ x, u16* __restrict__ xb){
  size_t i = ((size_t)blockIdx.x * 256 + threadIdx.x) * 8;
  float4 f0 = *reinterpret_cast<const float4*>(x + i);
  float4 f1 = *reinterpret_cast<const float4*>(x + i + 4);
  uint4 q;
  q.x = pkbf(f0.x, f0.y); q.y = pkbf(f0.z, f0.w);
  q.z = pkbf(f1.x, f1.y); q.w = pkbf(f1.z, f1.w);
  *reinterpret_cast<uint4*>(xb + i) = q;
}

// ======================================================================
// K2 v10b: WINDOW-MAJOR qkv GEMM. One (window g, sec) per block, 256 thr
// (4 waves = N-quarters), M=80 (72 tokens + 8 pad), K=384, N=384.
// A rows gathered per-token from xb via per-lane glds16 sources.
// Outputs:
//   q -> out u16 [g][h][72][64]            (window-head-tiled, full lines)
//   k -> out u16 +56623104, same layout
//   v -> vws [g][h][64ch][80tok] via in-LDS transpose, full-line stores,
//        tok 72..79 zeroed (PV padding).
// BUGFIX r10: table init grid-strided (288 entries > 256 threads).
// ======================================================================
#define WA_OFF 0        // A [80][64] bf16 swz : 10240
#define WB_OFF 10240    // B [384][64] bf16 swz : 49152 -> 59392
#define WVT    0        // v-transpose [384ch][80tok] (aliases A+B post-loop) : 61440
#define WTC    61440    // 288 f32
#define WTS    62592    // -> 63744
__launch_bounds__(256, 2)
__global__ void qkv_win(const u16* __restrict__ xb, const u16* __restrict__ wqb,
                        const float* __restrict__ bq, float* __restrict__ out,
                        u16* __restrict__ vws)
{
  __shared__ __align__(16) unsigned char smem[63744];
  const int tid  = threadIdx.x;
  const int wc   = tid >> 6;            // wave 0..3 : 96-col quarter
  const int lane = tid & 63;
  const int l15  = lane & 15;
  const int lhi  = lane >> 4;

  const int bid = blockIdx.x;           // 0..6143 (= 8 * 768)
  const int l   = (bid & 7) * 768 + (bid >> 3);
  const int g   = l / 3;                // global window 0..2047
  const int sec = l - g * 3;            // 0=q,1=k,2=v
  const int bIdx = g >> 10;
  const int win  = g & 1023;
  const int wi   = win >> 5;
  const int wj   = win & 31;

  auto rowof = [&](int t)->size_t {
    int r = t / 12, c = t - r * 12;
    int hh = wi * 6 + r + 3;  if (hh >= 192) hh -= 192;
    int ww = wj * 12 + c + 6; if (ww >= 384) ww -= 384;
    return ((size_t)bIdx * 192 + hh) * 384 + ww;
  };

  float* tabc = reinterpret_cast<float*>(smem + WTC);
  float* tabs = reinterpret_cast<float*>(smem + WTS);
  for (int i = tid; i < 288; i += 256){          // FIX: grid-stride (was if tid<288)
    int pos = i >> 4, m = i & 15;
    float pv = (pos < 6) ? (float)pos : (float)(pos - 6);
    float ang = pv * __expf(-(float)m * 0.5756462732485114f); // 10000^(-m/16)
    tabc[i] = cosf(ang);
    tabs[i] = sinf(ang);
  }

  // precompute A-chunk source rows (kk-invariant): chunks c = it*256+tid
  size_t arow[3]; int asoff[3]; bool aval[3];
  #pragma unroll
  for (int it = 0; it < 3; ++it){
    int c = it * 256 + tid;
    aval[it] = (it < 2) || (tid < 128);
    int t = c >> 3, p = c & 7;
    int tc = (t < 72) ? t : 71;
    arow[it]  = rowof(tc);
    asoff[it] = ((p ^ (t & 7)) << 3);
  }

  f32x4 acc[5][6];
  #pragma unroll
  for (int mt = 0; mt < 5; ++mt)
    #pragma unroll
    for (int nt = 0; nt < 6; ++nt) acc[mt][nt] = 0.0f;

  for (int kk = 0; kk < 6; ++kk){
    // stage A: 640 chunks (per-lane gathered rows)
    #pragma unroll
    for (int it = 0; it < 3; ++it){
      if (aval[it])
        glds16(xb + arow[it] * 384 + kk * 64 + asoff[it],
               smem + WA_OFF + (it * 256 + tid) * 16);
    }
    // stage B: 3072 chunks
    #pragma unroll
    for (int it = 0; it < 12; ++it){
      int c = it * 256 + tid;
      int n = c >> 3, p = c & 7;
      glds16(wqb + (size_t)(sec * 384 + n) * 384 + kk * 64 + ((p ^ (n & 7)) << 3),
             smem + WB_OFF + c * 16);
    }
    __syncthreads();
    #pragma unroll
    for (int ks = 0; ks < 2; ++ks){
      const int kEl = ks * 32 + lhi * 8;
      bf16x8 af[5], bfr[6];
      #pragma unroll
      for (int mt = 0; mt < 5; ++mt)
        af[mt] = lds_frag(smem, WA_OFF, mt * 16 + l15, 128, kEl);
      #pragma unroll
      for (int nt = 0; nt < 6; ++nt)
        bfr[nt] = lds_frag(smem, WB_OFF, wc * 96 + nt * 16 + l15, 128, kEl);
      __builtin_amdgcn_s_setprio(1);
      #pragma unroll
      for (int mt = 0; mt < 5; ++mt)
        #pragma unroll
        for (int nt = 0; nt < 6; ++nt)
          acc[mt][nt] = __builtin_amdgcn_mfma_f32_16x16x32_bf16(af[mt], bfr[nt], acc[mt][nt], 0, 0, 0);
      __builtin_amdgcn_s_setprio(0);
    }
    __syncthreads();
  }

  if (sec < 2){
    // bias + RoPE (+0.125 for q); store window-head-tiled [g][h][72][64]
    u16* qk = (u16*)out + (sec ? 56623104u : 0u) + (size_t)g * 27648;  // 6*4608
    #pragma unroll
    for (int nt = 0; nt < 6; ++nt){
      const int ch  = wc * 96 + nt * 16 + l15;
      const int h   = ch >> 6;
      const int chh = ch & 63;
      const float bias = bq[sec * 384 + ch];
      const int p2  = chh >> 1;
      const int m   = p2 & 15;
      const bool isR = (p2 < 16);
      const bool ev  = ((chh & 1) == 0);
      #pragma unroll
      for (int mt = 0; mt < 5; ++mt){
        #pragma unroll
        for (int r = 0; r < 4; ++r){
          const int tok = mt * 16 + lhi * 4 + r;
          float v = acc[mt][nt][r] + bias;
          float o = __shfl_xor(v, 1);
          int tr = tok / 12;
          int pos = isR ? tr : (6 + tok - tr * 12);
          float cc = tabc[pos * 16 + m], ssn = tabs[pos * 16 + m];
          float nv = ev ? (v * cc - o * ssn) : (o * ssn + v * cc);
          if (sec == 0) nv *= 0.125f;
          if (tok < 72)
            qk[(size_t)h * 4608 + tok * 64 + chh] = f2bf(nv);
        }
      }
    }
  } else {
    // v: bias, transpose in LDS [384ch][80tok], bulk store full lines
    #pragma unroll
    for (int nt = 0; nt < 6; ++nt){
      const int ch = wc * 96 + nt * 16 + l15;
      const float bv = bq[768 + ch];
      #pragma unroll
      for (int mt = 0; mt < 5; ++mt){
        const int tok0 = mt * 16 + lhi * 4;
        uint2 pk;
        pk.x = pkbf(acc[mt][nt][0] + bv, acc[mt][nt][1] + bv);
        pk.y = pkbf(acc[mt][nt][2] + bv, acc[mt][nt][3] + bv);
        *reinterpret_cast<uint2*>(smem + WVT + ch * 160 + tok0 * 2) = pk;
      }
    }
    __syncthreads();
    u16* vd = vws + (size_t)g * 30720;   // 6*64*80
    #pragma unroll
    for (int it = 0; it < 15; ++it){
      int c  = it * 256 + tid;           // 0..3839
      int ch = c / 10;
      int p  = c - ch * 10;
      uint4 val;
      if (p == 9){ val.x = 0; val.y = 0; val.z = 0; val.w = 0; }  // tok 72..79 = 0
      else val = *reinterpret_cast<const uint4*>(smem + WVT + c * 16);
      *reinterpret_cast<uint4*>(vd + (size_t)(ch >> 6) * 5120 + (ch & 63) * 80 + p * 8) = val;
    }
  }
}

// ============ K3 v10: per-window attention, ALL inputs linear glds16 ============
// q,k from out (window-head-tiled), v from vws [g][h][64][80] (pre-transposed,
// pads zeroed). attnout -> axb [row][384] u16. r4-proven structure.
#define QH4 0
#define KH4 10240
#define VT4 20480      // 64*160 + 256 guard -> 30976
#define SMEM4 30976
__launch_bounds__(320, 5)
__global__ void win_attn6(const u16* __restrict__ qkg,
                          const u16* __restrict__ vws,
                          float* __restrict__ out,
                          u16* __restrict__ axb)
{
  __shared__ __align__(16) unsigned char smem[SMEM4];
  const int tid  = threadIdx.x;
  const int wave = tid >> 6;
  const int lane = tid & 63;
  const int l15  = lane & 15;
  const int lhi  = lane >> 4;

  const int bid  = blockIdx.x;
  const int wgid = (bid & 7) * 256 + (bid >> 3);   // XCD swizzle = qkv's map
  const int bIdx = wgid >> 10;
  const int win  = wgid & 1023;
  const int wi   = win >> 5;
  const int wj   = win & 31;
  const bool maskWin = (wi == 31);
  const int g    = wgid;                // == bIdx*1024 + win

  auto rowof = [&](int t)->size_t {
    int r = t / 12, c = t - r * 12;
    int hh = wi * 6 + r + 3;  if (hh >= 192) hh -= 192;
    int ww = wj * 12 + c + 6; if (ww >= 384) ww -= 384;
    return ((size_t)bIdx * 192 + hh) * 384 + ww;
  };
  const int qtok = wave * 16 + l15;     // 0..79
  const bool tv = (qtok < 72);
  const size_t qrow = rowof(tv ? qtok : 71);

  const u16* qsl0 = qkg + (size_t)g * 27648;
  const u16* ksl0 = qkg + 56623104u + (size_t)g * 27648;
  const u16* vsl0 = vws + (size_t)g * 30720;

  // zero the VT guard (row-overhang reads for kEl>=80 land here)
  if (tid < 64) *reinterpret_cast<u32*>(smem + VT4 + 10240 + tid * 4) = 0u;

  float sv[5][4];
  #pragma unroll
  for (int a2 = 0; a2 < 5; ++a2)
    #pragma unroll
    for (int b2 = 0; b2 < 4; ++b2) sv[a2][b2] = 0.0f;

  for (int h = 0; h < 6; ++h){
    // ---- stage q,k (pre-swizzled src) and v (linear) : 1920 glds16 ----
    const u16* qsl = qsl0 + h * 4608;
    const u16* ksl = ksl0 + h * 4608;
    const u16* vsl = vsl0 + h * 5120;
    #pragma unroll
    for (int it = 0; it < 2; ++it){
      int c = it * 320 + tid;           // 0..639
      int t = c >> 3, p = c & 7;
      int tc = (t < 72) ? t : 71;
      int s = (p ^ (t & 7)) << 3;
      glds16(qsl + tc * 64 + s, smem + QH4 + c * 16);
      glds16(ksl + tc * 64 + s, smem + KH4 + c * 16);
      glds16(vsl + c * 8,       smem + VT4 + c * 16);
    }
    __syncthreads();                    // stage visible

    // ---- QK^T: C[i=k][j=q] ----
    f32x4 pf[5];
    #pragma unroll
    for (int nt = 0; nt < 5; ++nt) pf[nt] = 0.0f;
    __builtin_amdgcn_s_setprio(1);
    #pragma unroll
    for (int ks = 0; ks < 2; ++ks){
      const int kEl = ks * 32 + lhi * 8;
      bf16x8 qf = lds_frag(smem, QH4, qtok, 128, kEl);
      #pragma unroll
      for (int nt = 0; nt < 5; ++nt){
        bf16x8 kf = lds_frag(smem, KH4, nt * 16 + l15, 128, kEl);
        pf[nt] = __builtin_amdgcn_mfma_f32_16x16x32_bf16(kf, qf, pf[nt], 0, 0, 0);
      }
    }
    __builtin_amdgcn_s_setprio(0);

    // ---- mask + softmax over k ----
    float mx = -1e30f;
    #pragma unroll
    for (int nt = 0; nt < 5; ++nt)
      #pragma unroll
      for (int r = 0; r < 4; ++r){
        const int kk2 = nt * 16 + lhi * 4 + r;
        bool valid = (kk2 < 72) && (!maskWin || ((kk2 < 36) == (qtok < 36)));
        float val = valid ? pf[nt][r] : -1e30f;
        pf[nt][r] = val;
        mx = fmaxf(mx, val);
      }
    mx = fmaxf(mx, __shfl_xor(mx, 16));
    mx = fmaxf(mx, __shfl_xor(mx, 32));
    float sm = 0.0f;
    #pragma unroll
    for (int nt = 0; nt < 5; ++nt)
      #pragma unroll
      for (int r = 0; r < 4; ++r){
        float e = __expf(pf[nt][r] - mx);
        pf[nt][r] = e; sm += e;
      }
    sm += __shfl_xor(sm, 16);
    sm += __shfl_xor(sm, 32);
    const float inv = 1.0f / sm;
    u32 pp[5][2];                       // packed bf16 pairs: P[k..k+1][q=l15]
    #pragma unroll
    for (int nt = 0; nt < 5; ++nt){
      float p0 = pf[nt][0] * inv, p1 = pf[nt][1] * inv;
      float p2 = pf[nt][2] * inv, p3 = pf[nt][3] * inv;
      sv[nt][0] += p0; sv[nt][1] += p1; sv[nt][2] += p2; sv[nt][3] += p3;
      pp[nt][0] = pkbf(p0, p1);
      pp[nt][1] = pkbf(p2, p3);
    }

    // ---- PV: C[i=ch][j=q]; P B-frags via shfl; V^T direct from VT ----
    f32x4 oacc[4];
    #pragma unroll
    for (int nt = 0; nt < 4; ++nt) oacc[nt] = 0.0f;
    #pragma unroll
    for (int ks = 0; ks < 3; ++ks){
      FragU pb;
      u32 w[4];
      #pragma unroll
      for (int w_ = 0; w_ < 4; ++w_){
        int srcLane = l15 + 16 * ((lane >> 4 & 1) * 2 + (w_ >> 1));
        u32 c0 = __shfl(pp[ks * 2][w_ & 1], srcLane);
        u32 c1 = (ks * 2 + 1 < 5) ? __shfl(pp[ks * 2 + 1][w_ & 1], srcLane) : 0u;
        w[w_] = (lhi & 2) ? c1 : c0;
      }
      pb.u4.x = w[0]; pb.u4.y = w[1]; pb.u4.z = w[2]; pb.u4.w = w[3];
      const int kEl = ks * 32 + lhi * 8;
      __builtin_amdgcn_s_setprio(1);
      #pragma unroll
      for (int nt = 0; nt < 4; ++nt){
        FragU vf;
        vf.u4 = *reinterpret_cast<const uint4*>(smem + VT4 + (nt * 16 + l15) * 160 + kEl * 2);
        oacc[nt] = __builtin_amdgcn_mfma_f32_16x16x32_bf16(vf.bf, pb.bf, oacc[nt], 0, 0, 0);
      }
      __builtin_amdgcn_s_setprio(0);
    }
    if (tv){
      u16* ao = axb + qrow * 384 + h * 64;
      #pragma unroll
      for (int nt = 0; nt < 4; ++nt){
        uint2 pk;
        pk.x = pkbf(oacc[nt][0], oacc[nt][1]);
        pk.y = pkbf(oacc[nt][2], oacc[nt][3]);
        *reinterpret_cast<uint2*>(ao + nt * 16 + lhi * 4) = pk;
      }
    }
    __syncthreads();                    // all LDS reads done before next stage
  } // heads

  // ---- save_attn = mean over heads: so[q*72 + k] ----
  if (tv){
    float* so = out + 56623104ull + (size_t)wgid * 5184 + (size_t)qtok * 72;
    const float c6 = 1.0f / 6.0f;
    #pragma unroll
    for (int nt = 0; nt < 4; ++nt){
      float4 v4; v4.x = sv[nt][0]*c6; v4.y = sv[nt][1]*c6; v4.z = sv[nt][2]*c6; v4.w = sv[nt][3]*c6;
      *reinterpret_cast<float4*>(so + nt * 16 + lhi * 4) = v4;
    }
    if (lhi < 2){
      float4 v4; v4.x = sv[4][0]*c6; v4.y = sv[4][1]*c6; v4.z = sv[4][2]*c6; v4.w = sv[4][3]*c6;
      *reinterpret_cast<float4*>(so + 64 + lhi * 4) = v4;
    }
  }
}

// ======================================================================
// K4: out-projection GEMM (r7/r9 proven): tile M=128 x N=192, BK=32,
// 2-phase dbuf B, A frags direct from axb [row][384] u16. grid (1152, 2).
// ======================================================================
#define B6STR 12288
__launch_bounds__(512, 4)
__global__ void proj_gemm2(const u16* __restrict__ axb,
                           const u16* __restrict__ wpb, const float* __restrict__ bp,
                           float* __restrict__ out)
{
  __shared__ __align__(16) unsigned char smem[24576];
  const int tid  = threadIdx.x;
  const int wave = tid >> 6;
  const int lane = tid & 63;
  const int l15  = lane & 15;
  const int lhi  = lane >> 4;
  const int wr   = wave >> 2;
  const int wc   = wave & 3;
  const size_t row0 = (size_t)blockIdx.x * 128;
  const int ny   = blockIdx.y;

  const u16* bsec = wpb + (size_t)(ny * 192) * 384;
  auto stageB = [&](int t, int bufOff){
    {
      int c = tid, row = c >> 2, ccd = c & 3;
      int ccs = ccd ^ ((row >> 1) & 3);
      glds16(bsec + (size_t)row * 384 + t * 32 + ccs * 8, smem + bufOff + c * 16);
    }
    if (tid < 256){
      int c = 512 + tid, row = c >> 2, ccd = c & 3;
      int ccs = ccd ^ ((row >> 1) & 3);
      glds16(bsec + (size_t)row * 384 + t * 32 + ccs * 8, smem + bufOff + c * 16);
    }
  };

  const u16* abase = axb + (row0 + wr * 64 + l15) * 384 + lhi * 8;

  f32x4 acc[4][3];
  #pragma unroll
  for (int mt = 0; mt < 4; ++mt)
    #pragma unroll
    for (int nt = 0; nt < 3; ++nt) acc[mt][nt] = 0.0f;

  FragU a_cur[4], a_nxt[4];
  #pragma unroll
  for (int mt = 0; mt < 4; ++mt)
    a_cur[mt].u4 = *reinterpret_cast<const uint4*>(abase + mt * 6144);
  stageB(0, 0);
  __syncthreads();

  int buf = 0;
  for (int t = 0; t < 12; ++t){
    if (t < 11){
      stageB(t + 1, buf ^ B6STR);
      #pragma unroll
      for (int mt = 0; mt < 4; ++mt)
        a_nxt[mt].u4 = *reinterpret_cast<const uint4*>(abase + mt * 6144 + (t + 1) * 32);
    }
    FragU bfr[3];
    #pragma unroll
    for (int nt = 0; nt < 3; ++nt){
      int rown = wc * 48 + nt * 16 + l15;
      int byte = buf + rown * 64 + ((lhi ^ ((rown >> 1) & 3)) << 4);
      bfr[nt].u4 = *reinterpret_cast<const uint4*>(smem + byte);
    }
    #pragma unroll
    for (int mt = 0; mt < 4; ++mt)
      #pragma unroll
      for (int nt = 0; nt < 3; ++nt)
        acc[mt][nt] = __builtin_amdgcn_mfma_f32_16x16x32_bf16(a_cur[mt].bf, bfr[nt].bf, acc[mt][nt], 0, 0, 0);
    __syncthreads();
    #pragma unroll
    for (int mt = 0; mt < 4; ++mt) a_cur[mt] = a_nxt[mt];
    buf ^= B6STR;
  }

  float bpv[3];
  #pragma unroll
  for (int nt = 0; nt < 3; ++nt) bpv[nt] = bp[ny * 192 + wc * 48 + nt * 16 + l15];
  #pragma unroll
  for (int mt = 0; mt < 4; ++mt)
    #pragma unroll
    for (int nt = 0; nt < 3; ++nt){
      const int ch = ny * 192 + wc * 48 + nt * 16 + l15;
      #pragma unroll
      for (int r = 0; r < 4; ++r){
        size_t grow = row0 + wr * 64 + mt * 16 + lhi * 4 + r;
        out[grow * 384 + ch] = acc[mt][nt][r] + bpv[nt];
      }
    }
}

extern "C" void kernel_launch(void* const* d_in, const int* in_sizes, int n_in,
                              void* d_out, int out_size, void* d_ws, size_t ws_size,
                              hipStream_t stream)
{
  const float* x  = (const float*)d_in[0];
  const float* wq = (const float*)d_in[1];
  const float* bq = (const float*)d_in[2];
  const float* wp = (const float*)d_in[3];
  const float* bp = (const float*)d_in[4];
  float* out = (float*)d_out;

  u16* wqb = (u16*)d_ws;                              // 442368 bf16
  u16* wpb = (u16*)((char*)d_ws + 442368 * 2);        // 147456 bf16
  u16* vws = (u16*)((char*)d_ws + 1179648);           // 2048*6*64*80 bf16 (125.8 MB)
  u16* xb  = (u16*)((char*)d_ws + 127008768);         // 147456*384 bf16 (113.2 MB)
  // ws_size >= 240254976 confirmed by rounds 5/7/9 (big2 path ran).

  prep_weights<<<1728, 256, 0, stream>>>(wq, wp, wqb, wpb);
  prep_x<<<27648, 256, 0, stream>>>(x, xb);
  qkv_win<<<6144, 256, 0, stream>>>(xb, wqb, bq, out, vws);
  win_attn6<<<2048, 320, 0, stream>>>((const u16*)out, vws, out, xb);
  proj_gemm2<<<dim3(1152, 2), 512, 0, stream>>>(xb, wpb, bp, out);
}